// Round 1
// baseline (25336.044 us; speedup 1.0000x reference)
//
#include <hip/hip_runtime.h>
#include <hip/hip_bf16.h>

// LSTM DynamicRNN: B=128, T=512, D=256, H=512.
// Persistent-weights cooperative kernel: 128 blocks (2 batch-tiles x 64
// col-tiles), each block owns 8 hidden units (32 z-columns across 4 gates),
// keeps its [768 x 32] slice of [Wx;Wh] as register-resident bf16 MFMA
// B-fragments. One grid barrier per timestep via device-scope atomics
// (128 blocks <= 256 CUs => co-resident; __launch_bounds__(512,2) caps
// VGPRs at 256 so each 8-wave block fits one CU).

#define B_   128
#define T_   512
#define D_   256
#define H_   512
#define G4_  2048   // 4*H
#define NBLK 128
#define KS   24     // K = 768 = 24 k-steps of 32

typedef __attribute__((ext_vector_type(8))) short short8;
typedef __attribute__((ext_vector_type(4))) float float4v;

__device__ inline unsigned short f2bf_bits(float f) {
    union { float f; unsigned u; } v; v.f = f;
    unsigned r = (v.u + 0x7FFFu + ((v.u >> 16) & 1u)) >> 16;
    return (unsigned short)r;
}

__device__ inline float sigmoid_fast(float x) {
    return 1.f / (1.f + __expf(-x));
}

__device__ inline float tanh_fast(float x) {
    float a = fabsf(x);
    float e = __expf(-2.f * a);
    float r = (1.f - e) / (1.f + e);
    return copysignf(r, x);
}

union ABu { short8 s8; __hip_bfloat162 h2[4]; };

__global__ __launch_bounds__(512, 2) void lstm_persistent(
    const float* __restrict__ x, const float* __restrict__ Wx,
    const float* __restrict__ Wh, const float* __restrict__ bias,
    float* __restrict__ out, unsigned short* hbuf, unsigned int* bar)
{
    const int tid  = threadIdx.x;
    const int lane = tid & 63;
    const int wave = tid >> 6;      // 8 waves
    const int ms   = wave & 3;      // M-strip (16 rows each) within 64-batch tile
    const int nt   = wave >> 2;     // N-tile (16 cols each) within 32 cols
    const int ct   = blockIdx.x & 63;   // column tile: hidden units ct*8..ct*8+7
    const int bt   = blockIdx.x >> 6;   // batch tile: batches bt*64..bt*64+63
    const int jh0  = ct * 8;

    __shared__ float zls[64 * 33];   // z tile [64 batches][32 cols], padded
    __shared__ float cls[64 * 8];    // c state [64 batches][8 units]
    __shared__ float bls[32];        // bias slice

    for (int i = tid; i < 64 * 8; i += 512) cls[i] = 0.f;
    if (tid < 32) {
        int q = tid >> 3, u = tid & 7;
        bls[tid] = bias[q * 512 + jh0 + u];
    }

    // ---- load register-resident weight B-fragments (one-time) ----
    // B-frag layout (16x16x32 bf16): lane holds B[k=(lane>>4)*8+j][n=lane&15]
    const int l15 = lane & 15;
    const int l4  = lane >> 4;
    const int n   = nt * 16 + l15;       // 0..31 within block's columns
    const int q   = n >> 3, u = n & 7;
    const int col = q * 512 + jh0 + u;   // global z column
    short8 wfrag[KS];
#pragma unroll
    for (int ks = 0; ks < KS; ++ks) {
        short8 w;
#pragma unroll
        for (int j = 0; j < 8; ++j) {
            int k = ks * 32 + l4 * 8 + j;
            float v = (k < D_) ? Wx[(size_t)k * G4_ + col]
                               : Wh[(size_t)(k - D_) * G4_ + col];
            w[j] = (short)f2bf_bits(v);
        }
        wfrag[ks] = w;
    }

    __syncthreads();

    // A-frag addressing: lane holds A[m=lane&15][k=(lane>>4)*8+j]
    const int mrow = ms * 16 + l15;          // row within 64-batch tile
    const int gb_a = bt * 64 + mrow;         // global batch for A-frag
    const float* xrow = x + (size_t)gb_a * (T_ * D_);

    // gate-phase mapping: one thread per (batch, unit)
    const int bl   = tid >> 3;
    const int ug   = tid & 7;
    const int gb_g = bt * 64 + bl;

    int cur = 0;
    for (int t = 0; t < T_; ++t) {
        // ---- z = [x_t, h] @ [Wx; Wh]  (K=768) ----
        float4v acc = {0.f, 0.f, 0.f, 0.f};
        const float* xr = xrow + t * D_ + l4 * 8;
        const unsigned short* hb = hbuf + (size_t)cur * (B_ * H_)
                                        + (size_t)gb_a * H_ + l4 * 8;
#pragma unroll
        for (int ks = 0; ks < 8; ++ks) {   // x part (f32 -> bf16)
            float4v x0 = *(const float4v*)(xr + ks * 32);
            float4v x1 = *(const float4v*)(xr + ks * 32 + 4);
            ABu ab;
            ab.h2[0] = __float22bfloat162_rn(make_float2(x0[0], x0[1]));
            ab.h2[1] = __float22bfloat162_rn(make_float2(x0[2], x0[3]));
            ab.h2[2] = __float22bfloat162_rn(make_float2(x1[0], x1[1]));
            ab.h2[3] = __float22bfloat162_rn(make_float2(x1[2], x1[3]));
            acc = __builtin_amdgcn_mfma_f32_16x16x32_bf16(ab.s8, wfrag[ks], acc, 0, 0, 0);
        }
#pragma unroll
        for (int ks = 8; ks < KS; ++ks) {  // h part (bf16 direct)
            short8 a = *(const short8*)(hb + (ks - 8) * 32);
            acc = __builtin_amdgcn_mfma_f32_16x16x32_bf16(a, wfrag[ks], acc, 0, 0, 0);
        }
        // D layout: D[row=(lane>>4)*4+r][col=lane&15]
#pragma unroll
        for (int r = 0; r < 4; ++r) {
            int row = ms * 16 + l4 * 4 + r;
            zls[row * 33 + nt * 16 + l15] = acc[r];
        }
        __syncthreads();

        // ---- gates: one thread per (batch, unit) ----
        {
            float zi = zls[bl * 33 + ug]      + bls[ug];
            float zf = zls[bl * 33 + 8 + ug]  + bls[8 + ug];
            float zg = zls[bl * 33 + 16 + ug] + bls[16 + ug];
            float zo = zls[bl * 33 + 24 + ug] + bls[24 + ug];
            float ig = sigmoid_fast(zi);
            float fg = sigmoid_fast(zf);
            float gg = tanh_fast(zg);
            float og = sigmoid_fast(zo);
            float cold = cls[bl * 8 + ug];
            float cnew = fg * cold + ig * gg;
            float hnew = og * tanh_fast(cnew);
            cls[bl * 8 + ug] = cnew;
            hbuf[(size_t)(cur ^ 1) * (B_ * H_) + (size_t)gb_g * H_ + jh0 + ug]
                = f2bf_bits(hnew);
            out[(size_t)gb_g * (T_ * H_) + (size_t)t * H_ + jh0 + ug] = hnew;
            if (t == T_ - 1) {
                const size_t BTH = (size_t)B_ * T_ * H_;
                out[BTH + (size_t)gb_g * H_ + jh0 + ug] = hnew;
                out[BTH + (size_t)B_ * H_ + (size_t)gb_g * H_ + jh0 + ug] = cnew;
            }
        }

        // ---- grid barrier (device-scope) ----
        __threadfence();
        __syncthreads();
        if (tid == 0) {
            __hip_atomic_fetch_add(bar, 1u, __ATOMIC_RELEASE, __HIP_MEMORY_SCOPE_AGENT);
            unsigned target = (unsigned)(t + 1) * NBLK;
            while (__hip_atomic_load(bar, __ATOMIC_RELAXED, __HIP_MEMORY_SCOPE_AGENT) < target) { }
        }
        __syncthreads();
        __threadfence();
        cur ^= 1;
    }
}

extern "C" void kernel_launch(void* const* d_in, const int* in_sizes, int n_in,
                              void* d_out, int out_size, void* d_ws, size_t ws_size,
                              hipStream_t stream) {
    const float* x    = (const float*)d_in[0];
    const float* Wx   = (const float*)d_in[1];
    const float* Wh   = (const float*)d_in[2];
    const float* bias = (const float*)d_in[3];
    float* out = (float*)d_out;

    unsigned short* hbuf = (unsigned short*)d_ws;              // 2 x [128][512] bf16
    const size_t hbuf_bytes = (size_t)2 * B_ * H_ * sizeof(unsigned short);
    unsigned int* bar = (unsigned int*)((char*)d_ws + hbuf_bytes);

    // zero h0 and barrier counter (ws is re-poisoned 0xAA before every call)
    hipMemsetAsync(d_ws, 0, hbuf_bytes + 64, stream);

    lstm_persistent<<<dim3(NBLK), dim3(512), 0, stream>>>(
        x, Wx, Wh, bias, out, hbuf, bar);
}

// Round 2
// 5324.989 us; speedup vs baseline: 4.7580x; 4.7580x over previous
//
#include <hip/hip_runtime.h>
#include <hip/hip_bf16.h>

// LSTM DynamicRNN: B=128, T=512, D=256, H=512.
// Persistent-weights cooperative kernel, 128 blocks (2 batch-tiles x 64
// col-tiles). Round 2: replace __threadfence (agent fence => buffer_wbl2 +
// buffer_inv, full L2 nuke per step) with cache-bypassing relaxed agent
// atomics for the h exchange (sc0 sc1 -> coherent via shared L3), manual
// vmcnt drain for release, and a hierarchical 8-subcounter barrier.

#define B_   128
#define T_   512
#define D_   256
#define H_   512
#define G4_  2048   // 4*H
#define NBLK 128
#define NSUB 8
#define KS   24     // K = 768 = 24 k-steps of 32
#define KH   16     // h-part k-steps (K=512)

typedef __attribute__((ext_vector_type(8))) short short8;
typedef __attribute__((ext_vector_type(4))) float float4v;

__device__ inline unsigned short f2bf_bits(float f) {
    union { float f; unsigned u; } v; v.f = f;
    unsigned r = (v.u + 0x7FFFu + ((v.u >> 16) & 1u)) >> 16;
    return (unsigned short)r;
}

__device__ inline float sigmoid_fast(float x) {
    return 1.f / (1.f + __expf(-x));
}

__device__ inline float tanh_fast(float x) {
    float a = fabsf(x);
    float e = __expf(-2.f * a);
    float r = (1.f - e) / (1.f + e);
    return copysignf(r, x);
}

union ABu { short8 s8; __hip_bfloat162 h2[4]; unsigned long long u64[2]; };

__global__ __launch_bounds__(512, 2) void lstm_persistent(
    const float* __restrict__ x, const float* __restrict__ Wx,
    const float* __restrict__ Wh, const float* __restrict__ bias,
    float* __restrict__ out, unsigned long long* __restrict__ hbuf,
    unsigned int* __restrict__ bar)
{
    const int tid  = threadIdx.x;
    const int lane = tid & 63;
    const int wave = tid >> 6;      // 8 waves
    const int ms   = wave & 3;      // M-strip (16 rows) within 64-batch tile
    const int nt   = wave >> 2;     // N-tile (16 cols) within 32 cols
    const int ct   = blockIdx.x & 63;   // column tile: hidden units ct*8..+7
    const int bt   = blockIdx.x >> 6;   // batch tile: batches bt*64..+63
    const int jh0  = ct * 8;

    __shared__ float zls[64 * 33];      // z tile [64 batches][32 cols], padded
    __shared__ float cls[64 * 8];       // c state [64 batches][8 units]
    __shared__ float bls[32];           // bias slice
    __shared__ unsigned short hls[512]; // h bf16 staging [64 batches][8 units]

    for (int i = tid; i < 64 * 8; i += 512) cls[i] = 0.f;
    if (tid < 32) {
        int q = tid >> 3, u = tid & 7;
        bls[tid] = bias[q * 512 + jh0 + u];
    }

    // ---- register-resident weight B-fragments (one-time) ----
    // B-frag (16x16x32 bf16): lane holds B[k=(lane>>4)*8+j][n=lane&15]
    const int l15 = lane & 15;
    const int l4  = lane >> 4;
    const int n   = nt * 16 + l15;       // 0..31 within block's columns
    const int q   = n >> 3, u = n & 7;
    const int col = q * 512 + jh0 + u;   // global z column
    short8 wfrag[KS];
#pragma unroll
    for (int ks = 0; ks < KS; ++ks) {
        short8 w;
#pragma unroll
        for (int j = 0; j < 8; ++j) {
            int k = ks * 32 + l4 * 8 + j;
            float v = (k < D_) ? Wx[(size_t)k * G4_ + col]
                               : Wh[(size_t)(k - D_) * G4_ + col];
            w[j] = (short)f2bf_bits(v);
        }
        wfrag[ks] = w;
    }

    __syncthreads();

    // A-frag: lane holds A[m=lane&15][k=(lane>>4)*8+j]
    const int mrow = ms * 16 + l15;
    const int gb_a = bt * 64 + mrow;         // global batch for A-frag
    const float* xrow = x + (size_t)gb_a * (T_ * D_);

    // gate-phase mapping: one thread per (batch, unit)
    const int bl   = tid >> 3;
    const int ug   = tid & 7;
    const int gb_g = bt * 64 + bl;

    // h layout: [buf(2)][u_tile(64)][batch(128)][8 bf16] == 2 u64 per (ut,b)
    unsigned int* const sub    = bar;            // sub[i] at bar[i*16] (64B apart)
    unsigned int* const master = bar + 8 * 16;

    int cur = 0;
    for (int t = 0; t < T_; ++t) {
        // ---- z = [x_t, h] @ [Wx; Wh]  (K=768) ----
        float4v acc = {0.f, 0.f, 0.f, 0.f};

        // issue all h loads first (cache-bypassing, coherent via L3)
        unsigned long long hA[2 * KH];
#pragma unroll
        for (int ks = 0; ks < KH; ++ks) {
            int ut = ks * 4 + l4;
            size_t idx = (((size_t)cur * 64 + ut) * 128 + gb_a) * 2;
            hA[2 * ks]     = __hip_atomic_load(hbuf + idx,     __ATOMIC_RELAXED,
                                               __HIP_MEMORY_SCOPE_AGENT);
            hA[2 * ks + 1] = __hip_atomic_load(hbuf + idx + 1, __ATOMIC_RELAXED,
                                               __HIP_MEMORY_SCOPE_AGENT);
        }

        const float* xr = xrow + t * D_ + l4 * 8;
#pragma unroll
        for (int ks = 0; ks < 8; ++ks) {   // x part (f32 -> bf16)
            float4v x0 = *(const float4v*)(xr + ks * 32);
            float4v x1 = *(const float4v*)(xr + ks * 32 + 4);
            ABu ab;
            ab.h2[0] = __float22bfloat162_rn(make_float2(x0[0], x0[1]));
            ab.h2[1] = __float22bfloat162_rn(make_float2(x0[2], x0[3]));
            ab.h2[2] = __float22bfloat162_rn(make_float2(x1[0], x1[1]));
            ab.h2[3] = __float22bfloat162_rn(make_float2(x1[2], x1[3]));
            acc = __builtin_amdgcn_mfma_f32_16x16x32_bf16(ab.s8, wfrag[ks], acc, 0, 0, 0);
        }
#pragma unroll
        for (int ks = 0; ks < KH; ++ks) {  // h part
            ABu a;
            a.u64[0] = hA[2 * ks];
            a.u64[1] = hA[2 * ks + 1];
            acc = __builtin_amdgcn_mfma_f32_16x16x32_bf16(a.s8, wfrag[8 + ks], acc, 0, 0, 0);
        }
        // D layout: D[row=(lane>>4)*4+r][col=lane&15]
#pragma unroll
        for (int r = 0; r < 4; ++r) {
            int row = ms * 16 + l4 * 4 + r;
            zls[row * 33 + nt * 16 + l15] = acc[r];
        }
        __syncthreads();

        // ---- gates: one thread per (batch, unit) ----
        {
            float zi = zls[bl * 33 + ug]      + bls[ug];
            float zf = zls[bl * 33 + 8 + ug]  + bls[8 + ug];
            float zg = zls[bl * 33 + 16 + ug] + bls[16 + ug];
            float zo = zls[bl * 33 + 24 + ug] + bls[24 + ug];
            float ig = sigmoid_fast(zi);
            float fg = sigmoid_fast(zf);
            float gg = tanh_fast(zg);
            float og = sigmoid_fast(zo);
            float cold = cls[bl * 8 + ug];
            float cnew = fg * cold + ig * gg;
            float hnew = og * tanh_fast(cnew);
            cls[bl * 8 + ug] = cnew;
            hls[bl * 8 + ug] = f2bf_bits(hnew);
            out[(size_t)gb_g * (T_ * H_) + (size_t)t * H_ + jh0 + ug] = hnew;
            if (t == T_ - 1) {
                const size_t BTH = (size_t)B_ * T_ * H_;
                out[BTH + (size_t)gb_g * H_ + jh0 + ug] = hnew;
                out[BTH + (size_t)B_ * H_ + (size_t)gb_g * H_ + jh0 + ug] = cnew;
            }
        }
        __syncthreads();

        // ---- h store (wave 0: 64 lanes x 16B contiguous) + grid barrier ----
        if (wave == 0) {
            ABu hv;
            hv.s8 = *(const short8*)(hls + lane * 8);
            size_t widx = (((size_t)(cur ^ 1) * 64 + ct) * 128 + (bt * 64 + lane)) * 2;
            __hip_atomic_store(hbuf + widx,     hv.u64[0], __ATOMIC_RELAXED,
                               __HIP_MEMORY_SCOPE_AGENT);
            __hip_atomic_store(hbuf + widx + 1, hv.u64[1], __ATOMIC_RELAXED,
                               __HIP_MEMORY_SCOPE_AGENT);
            // release: drain stores to the coherence point (no buffer_wbl2!)
            asm volatile("s_waitcnt vmcnt(0)" ::: "memory");
            if (lane == 0) {
                const int sid = blockIdx.x & (NSUB - 1);
                unsigned old = __hip_atomic_fetch_add(&sub[sid * 16], 1u,
                                   __ATOMIC_RELAXED, __HIP_MEMORY_SCOPE_AGENT);
                if (old == (unsigned)t * 16u + 15u) {
                    __hip_atomic_fetch_add(master, 1u,
                        __ATOMIC_RELAXED, __HIP_MEMORY_SCOPE_AGENT);
                }
                unsigned target = (unsigned)(t + 1) * NSUB;
                while (__hip_atomic_load(master, __ATOMIC_RELAXED,
                                         __HIP_MEMORY_SCOPE_AGENT) < target) {
                    __builtin_amdgcn_s_sleep(2);
                }
            }
        }
        __syncthreads();
        cur ^= 1;
    }
}

extern "C" void kernel_launch(void* const* d_in, const int* in_sizes, int n_in,
                              void* d_out, int out_size, void* d_ws, size_t ws_size,
                              hipStream_t stream) {
    const float* x    = (const float*)d_in[0];
    const float* Wx   = (const float*)d_in[1];
    const float* Wh   = (const float*)d_in[2];
    const float* bias = (const float*)d_in[3];
    float* out = (float*)d_out;

    unsigned long long* hbuf = (unsigned long long*)d_ws;  // 2x[64][128][8] bf16
    const size_t hbuf_bytes = (size_t)2 * 64 * 128 * 8 * sizeof(unsigned short);
    unsigned int* bar = (unsigned int*)((char*)d_ws + hbuf_bytes);

    // zero h0 buffers and barrier counters (ws re-poisoned 0xAA each call)
    hipMemsetAsync(d_ws, 0, hbuf_bytes + 1024, stream);

    lstm_persistent<<<dim3(NBLK), dim3(512), 0, stream>>>(
        x, Wx, Wh, bias, out, hbuf, bar);
}

// Round 3
// 2916.827 us; speedup vs baseline: 8.6862x; 1.8256x over previous
//
#include <hip/hip_runtime.h>
#include <hip/hip_bf16.h>

// LSTM DynamicRNN: B=128, T=512, D=256, H=512.
// Persistent-weights cooperative kernel, 128 blocks (2 batch-tiles x 64
// col-tiles), grid barrier per step via L3-coherent relaxed agent atomics.
// Round 3: x-path off the critical chain — coalesced LDS staging of x_t
// (double-buffered, bf16, A-frag layout) + register prefetch of x_{t+1},
// with x-part MFMAs executed inside the barrier window. Critical path is
// now only: h-load(L3) -> 16 MFMAs -> gates -> h-store+drain -> barrier.

#define B_   128
#define T_   512
#define D_   256
#define H_   512
#define G4_  2048   // 4*H
#define NBLK 128
#define NSUB 8
#define KH   16     // h-part k-steps (K=512)
#define KX   8      // x-part k-steps (K=256)
#define XROW 264    // 256 + 8 pad (shorts) per staged x row

typedef __attribute__((ext_vector_type(8))) short short8;
typedef __attribute__((ext_vector_type(4))) short short4v;
typedef __attribute__((ext_vector_type(4))) float float4v;

__device__ inline unsigned short f2bf_bits(float f) {
    union { float f; unsigned u; } v; v.f = f;
    unsigned r = (v.u + 0x7FFFu + ((v.u >> 16) & 1u)) >> 16;
    return (unsigned short)r;
}

__device__ inline float sigmoid_fast(float x) {
    return 1.f / (1.f + __expf(-x));
}

__device__ inline float tanh_fast(float x) {
    float a = fabsf(x);
    float e = __expf(-2.f * a);
    float r = (1.f - e) / (1.f + e);
    return copysignf(r, x);
}

union ABu { short8 s8; unsigned long long u64[2]; };

__device__ inline short4v pack_bf4(float4v v) {
    short4v o;
    o[0] = (short)f2bf_bits(v[0]);
    o[1] = (short)f2bf_bits(v[1]);
    o[2] = (short)f2bf_bits(v[2]);
    o[3] = (short)f2bf_bits(v[3]);
    return o;
}

__global__ __launch_bounds__(512, 2) void lstm_persistent(
    const float* __restrict__ x, const float* __restrict__ Wx,
    const float* __restrict__ Wh, const float* __restrict__ bias,
    float* __restrict__ out, unsigned long long* __restrict__ hbuf,
    unsigned int* __restrict__ bar)
{
    const int tid  = threadIdx.x;
    const int lane = tid & 63;
    const int wave = tid >> 6;      // 8 waves
    const int ms   = wave & 3;      // M-strip (16 rows) within 64-batch tile
    const int nt   = wave >> 2;     // N-tile (16 cols) within 32 cols
    const int ct   = blockIdx.x & 63;   // column tile: hidden units ct*8..+7
    const int bt   = blockIdx.x >> 6;   // batch tile: batches bt*64..+63
    const int jh0  = ct * 8;

    __shared__ float zls[64 * 33];          // z tile, padded
    __shared__ float cls[64 * 8];           // c state
    __shared__ float bls[32];               // bias slice
    __shared__ unsigned short hls[512];     // h bf16 staging
    __shared__ unsigned short xls[2][64 * XROW];  // double-buffered x_t (bf16)

    for (int i = tid; i < 64 * 8; i += 512) cls[i] = 0.f;
    if (tid < 32) bls[tid] = bias[(tid >> 3) * 512 + jh0 + (tid & 7)];

    // ---- register-resident weight B-frags: ks 0..7 = Wx, ks 8..23 = Wh ----
    const int l15 = lane & 15;
    const int l4  = lane >> 4;
    const int ncol = nt * 16 + l15;
    const int col  = (ncol >> 3) * 512 + jh0 + (ncol & 7);
    short8 wfrag[KX + KH];
#pragma unroll
    for (int ks = 0; ks < KX + KH; ++ks) {
        short8 w;
#pragma unroll
        for (int j = 0; j < 8; ++j) {
            int k = ks * 32 + l4 * 8 + j;
            float v = (k < D_) ? Wx[(size_t)k * G4_ + col]
                               : Wh[(size_t)(k - D_) * G4_ + col];
            w[j] = (short)f2bf_bits(v);
        }
        wfrag[ks] = w;
    }

    // x staging mapping: 16 row-groups of 32 lanes, 512B-contiguous chunks
    const int srow = tid >> 5;          // 0..15
    const int scol = (tid & 31) * 4;    // 0,4,..,124
    const float* xbase = x + (size_t)(bt * 64) * (T_ * D_);

    // A-frag row (h and x): m = ms*16 + l15
    const int mrow = ms * 16 + l15;
    const int gb_a = bt * 64 + mrow;

    // gate-phase mapping
    const int bl = tid >> 3, ug = tid & 7;
    const int gb_g = bt * 64 + bl;

    unsigned int* const sub    = bar;          // sub[i] at bar[i*16]
    unsigned int* const master = bar + 8 * 16;

    // ---- prologue: stage x_0, x-part acc for t=0, prefetch x_1 ----
    float4v rx[8];
#pragma unroll
    for (int r = 0; r < 4; ++r) {
        const float* xp = xbase + (size_t)(r * 16 + srow) * (T_ * D_);
        rx[r * 2]     = *(const float4v*)(xp + scol);
        rx[r * 2 + 1] = *(const float4v*)(xp + scol + 128);
    }
#pragma unroll
    for (int r = 0; r < 4; ++r) {
        int row = r * 16 + srow;
        *(short4v*)(&xls[0][row * XROW + scol])       = pack_bf4(rx[r * 2]);
        *(short4v*)(&xls[0][row * XROW + scol + 128]) = pack_bf4(rx[r * 2 + 1]);
    }
    __syncthreads();
    float4v acc = {0.f, 0.f, 0.f, 0.f};
#pragma unroll
    for (int ks = 0; ks < KX; ++ks) {
        short8 a = *(const short8*)(&xls[0][mrow * XROW + ks * 32 + l4 * 8]);
        acc = __builtin_amdgcn_mfma_f32_16x16x32_bf16(a, wfrag[ks], acc, 0, 0, 0);
    }
    // prefetch x_1
#pragma unroll
    for (int r = 0; r < 4; ++r) {
        const float* xp = xbase + (size_t)(r * 16 + srow) * (T_ * D_) + 1 * D_;
        rx[r * 2]     = *(const float4v*)(xp + scol);
        rx[r * 2 + 1] = *(const float4v*)(xp + scol + 128);
    }

    int cur = 0;
    for (int t = 0; t < T_; ++t) {
        // ---- (a) h_t loads (L3-coherent, issued first for latency) ----
        unsigned long long hA[2 * KH];
#pragma unroll
        for (int ks = 0; ks < KH; ++ks) {
            int ut = ks * 4 + l4;
            size_t idx = (((size_t)cur * 64 + ut) * 128 + gb_a) * 2;
            hA[2 * ks]     = __hip_atomic_load(hbuf + idx,     __ATOMIC_RELAXED,
                                               __HIP_MEMORY_SCOPE_AGENT);
            hA[2 * ks + 1] = __hip_atomic_load(hbuf + idx + 1, __ATOMIC_RELAXED,
                                               __HIP_MEMORY_SCOPE_AGENT);
        }

        // ---- (b) write prefetched x_{t+1} into the other LDS buffer ----
        if (t + 1 < T_) {
            unsigned short* xb = xls[(t + 1) & 1];
#pragma unroll
            for (int r = 0; r < 4; ++r) {
                int row = r * 16 + srow;
                *(short4v*)(xb + row * XROW + scol)       = pack_bf4(rx[r * 2]);
                *(short4v*)(xb + row * XROW + scol + 128) = pack_bf4(rx[r * 2 + 1]);
            }
        }

        // ---- (c) h-part MFMAs (critical path) ----
#pragma unroll
        for (int ks = 0; ks < KH; ++ks) {
            ABu a;
            a.u64[0] = hA[2 * ks];
            a.u64[1] = hA[2 * ks + 1];
            acc = __builtin_amdgcn_mfma_f32_16x16x32_bf16(a.s8, wfrag[KX + ks], acc, 0, 0, 0);
        }
        // D layout: D[row=(lane>>4)*4+r][col=lane&15]
#pragma unroll
        for (int r = 0; r < 4; ++r) {
            int row = ms * 16 + l4 * 4 + r;
            zls[row * 33 + nt * 16 + l15] = acc[r];
        }
        __syncthreads();

        // ---- (e) gates ----
        {
            float zi = zls[bl * 33 + ug]      + bls[ug];
            float zf = zls[bl * 33 + 8 + ug]  + bls[8 + ug];
            float zg = zls[bl * 33 + 16 + ug] + bls[16 + ug];
            float zo = zls[bl * 33 + 24 + ug] + bls[24 + ug];
            float ig = sigmoid_fast(zi);
            float fg = sigmoid_fast(zf);
            float gg = tanh_fast(zg);
            float og = sigmoid_fast(zo);
            float cold = cls[bl * 8 + ug];
            float cnew = fg * cold + ig * gg;
            float hnew = og * tanh_fast(cnew);
            cls[bl * 8 + ug] = cnew;
            hls[bl * 8 + ug] = f2bf_bits(hnew);
            out[(size_t)gb_g * (T_ * H_) + (size_t)t * H_ + jh0 + ug] = hnew;
            if (t == T_ - 1) {
                const size_t BTH = (size_t)B_ * T_ * H_;
                out[BTH + (size_t)gb_g * H_ + jh0 + ug] = hnew;
                out[BTH + (size_t)B_ * H_ + (size_t)gb_g * H_ + jh0 + ug] = cnew;
            }
        }
        __syncthreads();

        // ---- (f) h_{t+1} store + arrive (wave0) ----
        if (wave == 0) {
            ABu hv;
            hv.s8 = *(const short8*)(hls + lane * 8);
            size_t widx = (((size_t)(cur ^ 1) * 64 + ct) * 128 + (bt * 64 + lane)) * 2;
            __hip_atomic_store(hbuf + widx,     hv.u64[0], __ATOMIC_RELAXED,
                               __HIP_MEMORY_SCOPE_AGENT);
            __hip_atomic_store(hbuf + widx + 1, hv.u64[1], __ATOMIC_RELAXED,
                               __HIP_MEMORY_SCOPE_AGENT);
            asm volatile("s_waitcnt vmcnt(0)" ::: "memory");  // release (no L2 nuke)
            if (lane == 0) {
                const int sid = blockIdx.x & (NSUB - 1);
                unsigned old = __hip_atomic_fetch_add(&sub[sid * 16], 1u,
                                   __ATOMIC_RELAXED, __HIP_MEMORY_SCOPE_AGENT);
                if (old == (unsigned)t * 16u + 15u) {
                    __hip_atomic_fetch_add(master, 1u,
                        __ATOMIC_RELAXED, __HIP_MEMORY_SCOPE_AGENT);
                }
            }
        }

        // ---- (g) barrier-window work: x-part MFMAs for t+1, prefetch t+2 ----
        float4v nacc = {0.f, 0.f, 0.f, 0.f};
        if (t + 1 < T_) {
            const unsigned short* xb = xls[(t + 1) & 1];
#pragma unroll
            for (int ks = 0; ks < KX; ++ks) {
                short8 a = *(const short8*)(xb + mrow * XROW + ks * 32 + l4 * 8);
                nacc = __builtin_amdgcn_mfma_f32_16x16x32_bf16(a, wfrag[ks], nacc, 0, 0, 0);
            }
            if (t + 2 < T_) {
#pragma unroll
                for (int r = 0; r < 4; ++r) {
                    const float* xp = xbase + (size_t)(r * 16 + srow) * (T_ * D_)
                                    + (size_t)(t + 2) * D_;
                    rx[r * 2]     = *(const float4v*)(xp + scol);
                    rx[r * 2 + 1] = *(const float4v*)(xp + scol + 128);
                }
            }
        }

        // ---- (h) poll ----
        if (wave == 0 && lane == 0) {
            unsigned target = (unsigned)(t + 1) * NSUB;
            while (__hip_atomic_load(master, __ATOMIC_RELAXED,
                                     __HIP_MEMORY_SCOPE_AGENT) < target) {
                __builtin_amdgcn_s_sleep(1);
            }
        }
        __syncthreads();
        acc = nacc;
        cur ^= 1;
    }
}

extern "C" void kernel_launch(void* const* d_in, const int* in_sizes, int n_in,
                              void* d_out, int out_size, void* d_ws, size_t ws_size,
                              hipStream_t stream) {
    const float* x    = (const float*)d_in[0];
    const float* Wx   = (const float*)d_in[1];
    const float* Wh   = (const float*)d_in[2];
    const float* bias = (const float*)d_in[3];
    float* out = (float*)d_out;

    unsigned long long* hbuf = (unsigned long long*)d_ws;  // 2x[64][128][8] bf16
    const size_t hbuf_bytes = (size_t)2 * 64 * 128 * 8 * sizeof(unsigned short);
    unsigned int* bar = (unsigned int*)((char*)d_ws + hbuf_bytes);

    hipMemsetAsync(d_ws, 0, hbuf_bytes + 1024, stream);

    lstm_persistent<<<dim3(NBLK), dim3(512), 0, stream>>>(
        x, Wx, Wh, bias, out, hbuf, bar);
}